// Round 3
// baseline (222.080 us; speedup 1.0000x reference)
//
#include <hip/hip_runtime.h>
#include <hip/hip_bf16.h>
#include <hip/hip_cooperative_groups.h>
#include <cstddef>

namespace cg = cooperative_groups;

typedef __attribute__((ext_vector_type(8))) short short8;
typedef __attribute__((ext_vector_type(4))) short short4v;
typedef __attribute__((ext_vector_type(4))) float floatx4;
typedef __hip_bfloat16 bf16;

#define NB 8
#define NC 256
#define ND 128
#define NN 3072
#define NT1 96            /* n-tile for phase 1/3: NN/96 = 32 tiles */
#define TILES 32
#define BN_EPS 1e-5f

static __device__ __forceinline__ short f2s(float v) {
    bf16 h = __float2bfloat16(v);
    return *reinterpret_cast<short*>(&h);
}

// LDS union: max member = phase2 (73.98 KB) -> 1 block/CU guaranteed.
union SMem {
    struct { short Ws[384][72]; short Xs[96][72]; } p1;   // K-loop: weights + x chunk
    struct { short PGs[256][104]; } p1e;                  // epilogue: phi/g projections
    struct { short As[256][136]; short Ms[16][136]; } p2; // w_w + reduced M slice
};

// ---------------------------------------------------------------------------
// mega: ONE cooperative kernel, grid 256 x 512 (1 block/CU), 2 grid syncs.
// Phase 1 (proj): block (b, n-tile 96). 8 waves x 48 rows of
//   [phi;g;theta](384) x 96 n, K=c=256. Weights staged fp32->bf16 per kt
//   (no setup kernel, no Wall). x: T14 reg-prefetch one kt ahead.
//   Epilogue: phi/g -> PGs; theta -> thT[b][n][d] (n-major, so phase 3
//   needs NO transpose staging). M-stage: M += phi.g^T over n=96 -> Mpart.
// Phase 2 (reduce+P2): block (b, e-slice of 4). Reduce 32 partials,
//   P2[c][e] = inv[c]*sum_d w_w[c][d]*M[e][d] -> P2g bf16.
// Phase 3 (final): block (b, n-tile 96). out = P2.theta^T + b2 + x.
//   A/B-frags DIRECT from global (P2g 512 KB, thT 6.3 MB - L2/L3 hot).
//   No LDS, no barriers in this phase.
// ---------------------------------------------------------------------------
__global__ __launch_bounds__(512, 2)
void mega_kernel(const float* __restrict__ x,
                 const float* __restrict__ g_w, const float* __restrict__ g_b,
                 const float* __restrict__ theta_w, const float* __restrict__ theta_b,
                 const float* __restrict__ phi_w, const float* __restrict__ phi_b,
                 const float* __restrict__ w_w, const float* __restrict__ w_b,
                 const float* __restrict__ gamma, const float* __restrict__ beta,
                 const float* __restrict__ mean, const float* __restrict__ var,
                 short* __restrict__ thT, float* __restrict__ Mpart,
                 short* __restrict__ P2g, float* __restrict__ out)
{
    __shared__ SMem sm;
    cg::grid_group grid = cg::this_grid();

    int t = threadIdx.x;
    int lane = t & 63;
    int wave = t >> 6;            // 0..7
    int lm = lane & 15;
    int lh = lane >> 4;           // 0..3
    int lk = lh * 8;

    int b = blockIdx.x >> 5;
    int tile = blockIdx.x & 31;
    int n0 = tile * NT1;

    floatx4 zero = {0.f, 0.f, 0.f, 0.f};

    // ================= phase 1: projections + M partials ==================
    {
        const float* xb = x + (size_t)b * NC * NN;

        floatx4 acc[3][6];
#pragma unroll
        for (int i = 0; i < 3; ++i)
#pragma unroll
            for (int j = 0; j < 6; ++j) acc[i][j] = zero;

        // x prefetch lanes: threads 0..383, 16 c-rows each
        int sn = t % 96;
        int cgp = t / 96;         // 0..3 (valid for t<384)
        float xf[16];
        if (t < 384) {
#pragma unroll
            for (int j = 0; j < 16; ++j)
                xf[j] = xb[(size_t)(cgp * 16 + j) * NN + n0 + sn];
        }

#pragma unroll
        for (int kt = 0; kt < NC; kt += 64) {
            __syncthreads();
            // stage weights [384 rows][64 k] fp32 -> bf16 (L2-hot, 384 KB total)
#pragma unroll
            for (int i = 0; i < 12; ++i) {
                int idx = t + i * 512;            // float4 id over 6144
                int row = idx >> 4;
                int c4 = (idx & 15) * 4;
                const float* sp = (row < 128) ? phi_w + (size_t)row * NC
                                : (row < 256) ? g_w + (size_t)(row - 128) * NC
                                              : theta_w + (size_t)(row - 256) * NC;
                floatx4 v = *(const floatx4*)(sp + kt + c4);
                short4v o;
#pragma unroll
                for (int j = 0; j < 4; ++j) o[j] = f2s(v[j]);
                *(short4v*)&sm.p1.Ws[row][c4] = o;
            }
            // write-late: x chunk from prefetched regs -> Xs[n][c-local]
            if (t < 384) {
                short8 s0, s1;
#pragma unroll
                for (int j = 0; j < 8; ++j) {
                    s0[j] = f2s(xf[j]);
                    s1[j] = f2s(xf[8 + j]);
                }
                *(short8*)&sm.p1.Xs[sn][cgp * 16]     = s0;
                *(short8*)&sm.p1.Xs[sn][cgp * 16 + 8] = s1;
            }
            __syncthreads();
            // issue-early: next kt's x (HBM latency hides under MFMAs)
            if (t < 384 && kt < NC - 64) {
#pragma unroll
                for (int j = 0; j < 16; ++j)
                    xf[j] = xb[(size_t)(kt + 64 + cgp * 16 + j) * NN + n0 + sn];
            }
#pragma unroll
            for (int h = 0; h < 64; h += 32) {
                short8 af[3], bfr[6];
#pragma unroll
                for (int i = 0; i < 3; ++i)
                    af[i] = *(const short8*)&sm.p1.Ws[wave * 48 + i * 16 + lm][h + lk];
#pragma unroll
                for (int j = 0; j < 6; ++j)
                    bfr[j] = *(const short8*)&sm.p1.Xs[j * 16 + lm][h + lk];
#pragma unroll
                for (int i = 0; i < 3; ++i)
#pragma unroll
                    for (int j = 0; j < 6; ++j)
                        acc[i][j] = __builtin_amdgcn_mfma_f32_16x16x32_bf16(
                            af[i], bfr[j], acc[i][j], 0, 0, 0);
            }
        }

        __syncthreads();   // done with Ws/Xs; PGs aliases them
        // epilogue: rows<256 -> PGs (phi/g); rows>=256 -> thT[b][n][d]
        int row_base = wave * 48 + lh * 4;
#pragma unroll
        for (int i = 0; i < 3; ++i) {
#pragma unroll
            for (int r = 0; r < 4; ++r) {
                int row = row_base + i * 16 + r;
                if (row < 256) {
                    float bv = (row < 128) ? phi_b[row] : g_b[row - 128];
#pragma unroll
                    for (int j = 0; j < 6; ++j)
                        sm.p1e.PGs[row][j * 16 + lm] = f2s(acc[i][j][r] + bv);
                } else {
                    int d = row - 256;
                    float bv = theta_b[d];
                    short* Tp = thT + ((size_t)b * NN + n0 + lm) * ND + d;
#pragma unroll
                    for (int j = 0; j < 6; ++j)
                        Tp[(size_t)(j * 16) * ND] = f2s(acc[i][j][r] + bv);
                }
            }
        }
        __syncthreads();

        // M-stage: M[e][d] += phi[e][n]*g[d][n] over n=96 (K=3x32)
        {
            int wr = wave >> 2;     // 0..1  -> e half (64)
            int wc = wave & 3;      // 0..3  -> d quarter (32)
            floatx4 macc[4][2];
#pragma unroll
            for (int i = 0; i < 4; ++i)
#pragma unroll
                for (int j = 0; j < 2; ++j) macc[i][j] = zero;
#pragma unroll
            for (int kk = 0; kk < 96; kk += 32) {
                short8 af[4], bfr[2];
#pragma unroll
                for (int i = 0; i < 4; ++i)
                    af[i] = *(const short8*)&sm.p1e.PGs[wr * 64 + i * 16 + lm][kk + lk];
#pragma unroll
                for (int j = 0; j < 2; ++j)
                    bfr[j] = *(const short8*)&sm.p1e.PGs[128 + wc * 32 + j * 16 + lm][kk + lk];
#pragma unroll
                for (int i = 0; i < 4; ++i)
#pragma unroll
                    for (int j = 0; j < 2; ++j)
                        macc[i][j] = __builtin_amdgcn_mfma_f32_16x16x32_bf16(
                            af[i], bfr[j], macc[i][j], 0, 0, 0);
            }
            float* Mf = Mpart + (size_t)blockIdx.x * (ND * ND);
            const float sc = 1.f / (float)NN;
#pragma unroll
            for (int i = 0; i < 4; ++i)
#pragma unroll
                for (int j = 0; j < 2; ++j)
#pragma unroll
                    for (int r = 0; r < 4; ++r)
                        Mf[(size_t)(wr * 64 + i * 16 + lh * 4 + r) * ND
                           + wc * 32 + j * 16 + lm] = macc[i][j][r] * sc;
        }
    }

    // ================= phase 2: reduce + P2 GEMM ==========================
    grid.sync();
    {
        int e0 = tile * 4;   // 32 e-slices of 4
        // stage w_w (256x128 fp32) -> As bf16
#pragma unroll
        for (int i = 0; i < 16; ++i) {
            int idx = t + i * 512;            // float4 id over 8192
            int c = idx >> 5;
            int d4 = (idx & 31) * 4;
            floatx4 v = *(const floatx4*)(w_w + (size_t)idx * 4);
            short4v o;
#pragma unroll
            for (int j = 0; j < 4; ++j) o[j] = f2s(v[j]);
            *(short4v*)&sm.p2.As[c][d4] = o;
        }
        // zero Ms pad rows 4..15
        if (t < 384) {
            short4v z = {0, 0, 0, 0};
            *(short4v*)&sm.p2.Ms[4 + (t >> 5)][(t & 31) * 4] = z;
        }
        // reduce 32 partials for 4 e-rows
        if (t < 128) {
            int e = t >> 5;
            int d4 = (t & 31) * 4;
            const float* src = Mpart + (size_t)b * (TILES * ND * ND)
                             + (size_t)(e0 + e) * ND + d4;
            floatx4 s = zero;
#pragma unroll 8
            for (int p = 0; p < TILES; ++p)
                s += *(const floatx4*)(src + (size_t)p * (ND * ND));
            short4v o;
#pragma unroll
            for (int j = 0; j < 4; ++j) o[j] = f2s(s[j]);
            *(short4v*)&sm.p2.Ms[e][d4] = o;
        }
        __syncthreads();
        // P2[c][e] GEMM, K=d=128; wave owns 32 c-rows
        floatx4 pacc[2];
        pacc[0] = zero; pacc[1] = zero;
#pragma unroll
        for (int kk = 0; kk < 128; kk += 32) {
            short8 bfr = *(const short8*)&sm.p2.Ms[lm][kk + lk];
#pragma unroll
            for (int i = 0; i < 2; ++i) {
                short8 af = *(const short8*)&sm.p2.As[wave * 32 + i * 16 + lm][kk + lk];
                pacc[i] = __builtin_amdgcn_mfma_f32_16x16x32_bf16(
                    af, bfr, pacc[i], 0, 0, 0);
            }
        }
        if (lm < 4) {
            int e = e0 + lm;
#pragma unroll
            for (int i = 0; i < 2; ++i) {
#pragma unroll
                for (int r = 0; r < 4; ++r) {
                    int c = wave * 32 + i * 16 + lh * 4 + r;
                    float iv = gamma[c] * rsqrtf(var[c] + BN_EPS);
                    P2g[((size_t)b * NC + c) * ND + e] = f2s(pacc[i][r] * iv);
                }
            }
        }
    }

    // ================= phase 3: out = P2.theta^T + b2 + x =================
    grid.sync();
    {
        int wr = wave >> 1;     // 0..3 -> c quarter (64)
        int wc = wave & 1;      // 0..1 -> n half (48)
        const short* P2b = P2g + (size_t)b * NC * ND;
        const short* Tb = thT + (size_t)b * NN * ND;

        floatx4 acc2[4][3];
#pragma unroll
        for (int i = 0; i < 4; ++i)
#pragma unroll
            for (int j = 0; j < 3; ++j) acc2[i][j] = zero;

#pragma unroll
        for (int kk = 0; kk < 128; kk += 32) {
            short8 af[4], bfr[3];
#pragma unroll
            for (int i = 0; i < 4; ++i)
                af[i] = *(const short8*)(P2b
                        + (size_t)(wr * 64 + i * 16 + lm) * ND + kk + lk);
#pragma unroll
            for (int j = 0; j < 3; ++j)
                bfr[j] = *(const short8*)(Tb
                        + (size_t)(n0 + wc * 48 + j * 16 + lm) * ND + kk + lk);
#pragma unroll
            for (int i = 0; i < 4; ++i)
#pragma unroll
                for (int j = 0; j < 3; ++j)
                    acc2[i][j] = __builtin_amdgcn_mfma_f32_16x16x32_bf16(
                        af[i], bfr[j], acc2[i][j], 0, 0, 0);
        }

        float* Cf = out + (size_t)b * NC * NN;
        const float* Rg = x + (size_t)b * NC * NN;
#pragma unroll
        for (int i = 0; i < 4; ++i) {
#pragma unroll
            for (int r = 0; r < 4; ++r) {
                int c = wr * 64 + i * 16 + lh * 4 + r;
                float iv = gamma[c] * rsqrtf(var[c] + BN_EPS);
                float b2 = iv * (w_b[c] - mean[c]) + beta[c];
#pragma unroll
                for (int j = 0; j < 3; ++j) {
                    size_t idx = (size_t)c * NN + n0 + wc * 48 + j * 16 + lm;
                    Cf[idx] = acc2[i][j][r] + b2 + Rg[idx];
                }
            }
        }
    }
}

extern "C" void kernel_launch(void* const* d_in, const int* in_sizes, int n_in,
                              void* d_out, int out_size, void* d_ws, size_t ws_size,
                              hipStream_t stream)
{
    const float* x       = (const float*)d_in[0];
    const float* g_w     = (const float*)d_in[1];
    const float* g_b     = (const float*)d_in[2];
    const float* theta_w = (const float*)d_in[3];
    const float* theta_b = (const float*)d_in[4];
    const float* phi_w   = (const float*)d_in[5];
    const float* phi_b   = (const float*)d_in[6];
    const float* w_w     = (const float*)d_in[7];
    const float* w_b     = (const float*)d_in[8];
    const float* gamma   = (const float*)d_in[9];
    const float* beta    = (const float*)d_in[10];
    const float* mean    = (const float*)d_in[11];
    const float* var     = (const float*)d_in[12];
    (void)in_sizes; (void)n_in; (void)out_size; (void)ws_size;

    char* w = (char*)d_ws;
    short* thT   = (short*)w; w += (size_t)NB * NN * ND * 2;           // 6.3 MB
    float* Mpart = (float*)w; w += (size_t)NB * TILES * ND * ND * 4;   // 16.8 MB
    short* P2g   = (short*)w; w += (size_t)NB * NC * ND * 2;           // 512 KB
    float* outp  = (float*)d_out;

    void* kargs[] = {
        (void*)&x, (void*)&g_w, (void*)&g_b, (void*)&theta_w, (void*)&theta_b,
        (void*)&phi_w, (void*)&phi_b, (void*)&w_w, (void*)&w_b,
        (void*)&gamma, (void*)&beta, (void*)&mean, (void*)&var,
        (void*)&thT, (void*)&Mpart, (void*)&P2g, (void*)&outp
    };
    hipLaunchCooperativeKernel((void*)mega_kernel, dim3(NB * TILES), dim3(512),
                               kargs, 0, stream);
}